// Round 1
// baseline (158.853 us; speedup 1.0000x reference)
//
#include <hip/hip_runtime.h>

// PointSIFT: octant-wise nearest neighbor within radius + group.
// B=2, N=4096, C=64 fixed by the problem.
#define BB 2
#define NN 4096
#define CC 64
#define QPB 32              // queries per block
#define TPQ 8               // threads per query (one candidate stripe each)
#define NT (QPB * TPQ)      // 256 threads per block

// flat output layout (all float32):
//   out0 grouped_xyz   [B,N,8,3]
//   out1 grouped_points[B,N,8,67]
//   out2 idx (as float)[B,N,8]
#define OUT0_OFF 0
#define OUT1_OFF (BB * NN * 8 * 3)               /* 196608 */
#define OUT2_OFF (OUT1_OFF + BB * NN * 8 * 67)   /* 4587520 */

__global__ __launch_bounds__(NT) void pointsift_select(
    const float* __restrict__ xyz, const float* __restrict__ radius_p,
    float* __restrict__ out)
{
    __shared__ float s_xyz[NN * 3];            // 48 KiB: whole batch's coords
    __shared__ float s_bd[8 * NT];             // per-thread per-octant best dist
    __shared__ unsigned short s_bi[8 * NT];    // per-thread per-octant best idx

    const int tid = threadIdx.x;
    const int blocks_per_batch = NN / QPB;     // 128
    const int b = blockIdx.x / blocks_per_batch;
    const int qbase = (blockIdx.x % blocks_per_batch) * QPB;

    // cooperative float4 load of this batch's xyz into LDS (3072 float4s)
    {
        const float4* src4 = (const float4*)(xyz + (size_t)b * NN * 3);
        float4* dst4 = (float4*)s_xyz;
        #pragma unroll
        for (int i = 0; i < (NN * 3 / 4) / NT; ++i)
            dst4[tid + i * NT] = src4[tid + i * NT];
    }

    const float r = radius_p[0];
    const float judge = __fmul_rn(r, r);

    const int n = qbase + (tid >> 3);          // query index within batch
    const int sub = tid & 7;                   // candidate stripe id

    // seed every octant with the diagonal entry: (judge, n)
    #pragma unroll
    for (int o = 0; o < 8; ++o) {
        s_bd[o * NT + tid] = judge;
        s_bi[o * NT + tid] = (unsigned short)n;
    }
    __syncthreads();

    const float qx = s_xyz[n * 3 + 0];
    const float qy = s_xyz[n * 3 + 1];
    const float qz = s_xyz[n * 3 + 2];

    // scan candidate stripe p = sub, sub+8, ... (ascending -> first-min kept)
    for (int p = sub; p < NN; p += TPQ) {
        float sx = s_xyz[p * 3 + 0];
        float sy = s_xyz[p * 3 + 1];
        float sz = s_xyz[p * 3 + 2];
        // diff = candidate - query, fp32, no contraction (must match numpy ref)
        float dx = __fsub_rn(sx, qx);
        float dy = __fsub_rn(sy, qy);
        float dz = __fsub_rn(sz, qz);
        float dist = __fadd_rn(__fadd_rn(__fmul_rn(dx, dx), __fmul_rn(dy, dy)),
                               __fmul_rn(dz, dz));
        // octant code: truncation of (diff + 1.0f), dotted with [4,2,1]
        int code = ((int)__fadd_rn(dx, 1.0f)) * 4 +
                   ((int)__fadd_rn(dy, 1.0f)) * 2 +
                   ((int)__fadd_rn(dz, 1.0f));
        if (dist < judge && dist > 1e-10f) {
            int a = code * NT + tid;           // own LDS column -> race-free
            if (dist < s_bd[a]) { s_bd[a] = dist; s_bi[a] = (unsigned short)p; }
        }
    }
    // no barrier needed: each thread reads back only its own column

    float bd[8]; int bi[8];
    #pragma unroll
    for (int o = 0; o < 8; ++o) {
        bd[o] = s_bd[o * NT + tid];
        bi[o] = (int)s_bi[o * NT + tid];
    }

    // butterfly reduce over the 8 stripe-threads of this query
    // (lanes are 8-aligned within the wave); tie-break: smaller index wins
    #pragma unroll
    for (int m = 1; m < TPQ; m <<= 1) {
        #pragma unroll
        for (int o = 0; o < 8; ++o) {
            float od = __shfl_xor(bd[o], m, 64);
            int   oi = __shfl_xor(bi[o], m, 64);
            if (od < bd[o] || (od == bd[o] && oi < bi[o])) {
                bd[o] = od; bi[o] = oi;
            }
        }
    }

    if (sub == 0) {
        const size_t base = ((size_t)b * NN + n) * 8;
        #pragma unroll
        for (int o = 0; o < 8; ++o) {
            int i = bi[o];
            out[OUT2_OFF + base + o] = (float)i;   // idx as float
            float gx = __fsub_rn(s_xyz[i * 3 + 0], qx);
            float gy = __fsub_rn(s_xyz[i * 3 + 1], qy);
            float gz = __fsub_rn(s_xyz[i * 3 + 2], qz);
            size_t o0 = (base + (size_t)o) * 3;
            out[OUT0_OFF + o0 + 0] = gx;
            out[OUT0_OFF + o0 + 1] = gy;
            out[OUT0_OFF + o0 + 2] = gz;
        }
    }
}

// grouped_points[b,n,j,c] = c<3 ? grouped_xyz[b,n,j,c] : points[b, idx[b,n,j], c-3]
__global__ __launch_bounds__(256) void pointsift_gather(
    const float* __restrict__ points, float* out)
{
    const unsigned total = BB * NN * 8 * 67;
    unsigned f = blockIdx.x * 256u + threadIdx.x;
    if (f >= total) return;
    unsigned rest = f / 67u;                 // (b*N + n)*8 + j
    unsigned c = f - rest * 67u;
    float v;
    if (c < 3u) {
        v = out[OUT0_OFF + rest * 3u + c];
    } else {
        unsigned bq = rest >> 3;             // b*N + n
        unsigned b = bq >> 12;               // / 4096
        int pidx = (int)out[OUT2_OFF + rest];
        v = points[((size_t)b * NN + (unsigned)pidx) * CC + (c - 3u)];
    }
    out[OUT1_OFF + f] = v;
}

extern "C" void kernel_launch(void* const* d_in, const int* in_sizes, int n_in,
                              void* d_out, int out_size, void* d_ws, size_t ws_size,
                              hipStream_t stream) {
    const float* xyz    = (const float*)d_in[0];
    const float* points = (const float*)d_in[1];
    const float* radius = (const float*)d_in[2];
    float* out = (float*)d_out;

    // kernel 1: octant select + grouped_xyz + idx
    hipLaunchKernelGGL(pointsift_select, dim3(BB * NN / QPB), dim3(NT), 0, stream,
                       xyz, radius, out);
    // kernel 2: feature gather into grouped_points (reads out0/out2, writes out1)
    const unsigned total1 = BB * NN * 8 * 67;
    hipLaunchKernelGGL(pointsift_gather, dim3((total1 + 255u) / 256u), dim3(256), 0,
                       stream, points, out);
}

// Round 2
// 129.286 us; speedup vs baseline: 1.2287x; 1.2287x over previous
//
#include <hip/hip_runtime.h>

// PointSIFT: octant-wise nearest neighbor within radius + group. Fused kernel.
// B=2, N=4096, C=64 fixed by the problem.
#define BB 2
#define NN 4096
#define CC 64
#define QPB 16              // queries per block
#define TPQ 16              // threads per query (one candidate stripe each)
#define NT (QPB * TPQ)      // 256 threads per block
#define BIGF 1e10f

// flat output layout (all float32):
//   out0 grouped_xyz   [B,N,8,3]
//   out1 grouped_points[B,N,8,67]
//   out2 idx (as float)[B,N,8]
#define OUT0_OFF 0
#define OUT1_OFF (BB * NN * 8 * 3)               /* 196608 */
#define OUT2_OFF (OUT1_OFF + BB * NN * 8 * 67)   /* 4587520 */

__global__ __launch_bounds__(NT) void pointsift_fused(
    const float* __restrict__ xyz, const float* __restrict__ points,
    const float* __restrict__ radius_p, float* __restrict__ out)
{
    __shared__ float s_xyz4[NN * 4];          // 64 KiB: padded float4 coords
    __shared__ int   s_sel[QPB * 8];          // selected idx per (query,octant)

    const int tid = threadIdx.x;
    const int blocks_per_batch = NN / QPB;    // 256
    const int b = blockIdx.x / blocks_per_batch;
    const int qbase = (blockIdx.x % blocks_per_batch) * QPB;

    // stage this batch's xyz into LDS, padded to float4 stride
    {
        const float* src = xyz + (size_t)b * NN * 3;
        for (int p = tid; p < NN; p += NT) {
            float x = src[p * 3 + 0];
            float y = src[p * 3 + 1];
            float z = src[p * 3 + 2];
            float4* d = (float4*)(s_xyz4 + p * 4);
            *d = make_float4(x, y, z, 0.0f);
        }
    }

    const float r = radius_p[0];
    const float judge = __fmul_rn(r, r);

    const int n = qbase + (tid >> 4);         // query index within batch
    const int sub = tid & (TPQ - 1);          // candidate stripe id

    __syncthreads();

    const float qx = s_xyz4[n * 4 + 0];
    const float qy = s_xyz4[n * 4 + 1];
    const float qz = s_xyz4[n * 4 + 2];

    // register scoreboard, seeded with the diagonal entry (judge, n)
    float bd[8]; int bi[8];
    #pragma unroll
    for (int o = 0; o < 8; ++o) { bd[o] = judge; bi[o] = n; }

    // scan candidate stripe p = sub, sub+16, ... (ascending -> first-min kept)
    const float4* sx4 = (const float4*)s_xyz4;
    #pragma unroll 4
    for (int p = sub; p < NN; p += TPQ) {
        float4 c = sx4[p];
        // diff = candidate - query, fp32, no contraction (must match numpy ref)
        float dx = __fsub_rn(c.x, qx);
        float dy = __fsub_rn(c.y, qy);
        float dz = __fsub_rn(c.z, qz);
        float dist = __fadd_rn(__fadd_rn(__fmul_rn(dx, dx), __fmul_rn(dy, dy)),
                               __fmul_rn(dz, dz));
        // octant code: truncation of (diff + 1.0f), dotted with [4,2,1]
        int code = ((int)__fadd_rn(dx, 1.0f)) * 4 +
                   ((int)__fadd_rn(dy, 1.0f)) * 2 +
                   ((int)__fadd_rn(dz, 1.0f));
        bool valid = (dist < judge) & (dist > 1e-10f);
        float dv = valid ? dist : BIGF;       // BIGF always loses to seed judge
        #pragma unroll
        for (int o = 0; o < 8; ++o) {
            bool m = (code == o) & (dv < bd[o]);
            bd[o] = m ? dv : bd[o];
            bi[o] = m ? p  : bi[o];
        }
    }

    // butterfly reduce over the 16 stripe-threads of this query
    // (lanes are 16-aligned within the wave); tie-break: smaller index wins
    #pragma unroll
    for (int m = 1; m < TPQ; m <<= 1) {
        #pragma unroll
        for (int o = 0; o < 8; ++o) {
            float od = __shfl_xor(bd[o], m, 64);
            int   oi = __shfl_xor(bi[o], m, 64);
            if (od < bd[o] || (od == bd[o] && oi < bi[o])) {
                bd[o] = od; bi[o] = oi;
            }
        }
    }

    // publish selected indices to LDS (lanes sub<8 each publish one octant)
    if (sub < 8) s_sel[(tid >> 4) * 8 + sub] = bi[sub];
    __syncthreads();

    // fused gather: wave per (query,octant) pair; lane c handles channel c.
    // QPB*8 = 128 pairs, 4 waves/block -> 32 iterations each.
    const int wave = tid >> 6;
    const int lane = tid & 63;
    const float* prow = points + (size_t)b * NN * CC;
    for (int pid = wave; pid < QPB * 8; pid += NT / 64) {
        const int q = pid >> 3;
        const int o = pid & 7;
        const int i = s_sel[pid];
        const int nq = qbase + q;
        const size_t rest = ((size_t)b * NN + nq) * 8 + o;
        // features: lane c -> out1[rest*67 + 3 + c]
        float f = prow[(size_t)i * CC + lane];
        out[OUT1_OFF + rest * 67 + 3 + lane] = f;
        if (lane < 3) {
            float g = __fsub_rn(s_xyz4[i * 4 + lane], s_xyz4[nq * 4 + lane]);
            out[OUT0_OFF + rest * 3 + lane] = g;
            out[OUT1_OFF + rest * 67 + lane] = g;
        } else if (lane == 3) {
            out[OUT2_OFF + rest] = (float)i;  // idx as float
        }
    }
}

extern "C" void kernel_launch(void* const* d_in, const int* in_sizes, int n_in,
                              void* d_out, int out_size, void* d_ws, size_t ws_size,
                              hipStream_t stream) {
    const float* xyz    = (const float*)d_in[0];
    const float* points = (const float*)d_in[1];
    const float* radius = (const float*)d_in[2];
    float* out = (float*)d_out;

    hipLaunchKernelGGL(pointsift_fused, dim3(BB * NN / QPB), dim3(NT), 0, stream,
                       xyz, points, radius, out);
}